// Round 19
// baseline (246.784 us; speedup 1.0000x reference)
//
#include <hip/hip_runtime.h>

#define Bb 32
#define Nn 512
#define Dd 256
#define KC 1792   // 256 (self) + 6*256 (edge types)
#define NR (Bb * Nn)   // 16384 rows

typedef __bf16 bf16x8 __attribute__((ext_vector_type(8)));
typedef float  f32x4  __attribute__((ext_vector_type(4)));
typedef int    i32x4  __attribute__((ext_vector_type(4)));
typedef unsigned short u16;

__device__ __forceinline__ u16 f2bf(float x){
  union { float f; unsigned u; } c; c.f = x;
  unsigned u = c.u;
  u += 0x7FFFu + ((u >> 16) & 1u);   // RNE
  return (u16)(u >> 16);
}

// ---------------- K0: WcatT[e][c] = Wcat[c][e] in bf16, [256 x 1792] -------
__global__ __launch_bounds__(256) void k_prep(
    const float* __restrict__ wself,
    const float* __restrict__ w0, const float* __restrict__ w1,
    const float* __restrict__ w2, const float* __restrict__ w3,
    const float* __restrict__ w4, const float* __restrict__ w5,
    u16* __restrict__ wcatT){
  int e = blockIdx.x;
  const float* Ws[7] = {wself, w0, w1, w2, w3, w4, w5};
  for (int c = threadIdx.x; c < KC; c += 256){
    int g = c >> 8, j = c & 255;
    wcatT[(size_t)e*KC + c] = f2bf(Ws[g][j*Dd + e]);
  }
}

// ---------------- K2: dw (sigmoid), Nbf bf16 node copy, Xp = dw*node -------
__global__ __launch_bounds__(256) void k_dw(
    const float* __restrict__ node, const int* __restrict__ mask,
    const float* __restrict__ wnw, const float* __restrict__ bnw,
    float* __restrict__ aw_out,    // already offset by t*N
    u16* __restrict__ Nbf, u16* __restrict__ Xp){
  __shared__ float tile[32][268];
  __shared__ float dws[32];
  int b = blockIdx.x >> 4, n0 = (blockIdx.x & 15) << 5;
  int t = threadIdx.x;
  int row = t >> 3, seg = t & 7;
  const float* src = node + ((size_t)(b * Nn + n0 + row)) * Dd + seg * 32;
  u16* zn = Nbf + ((size_t)(b * Nn + n0 + row)) * Dd + seg * 32;
  #pragma unroll
  for (int c = 0; c < 8; ++c){
    float4 v = ((const float4*)src)[c];
    tile[row][seg * 32 + c * 4 + 0] = v.x;
    tile[row][seg * 32 + c * 4 + 1] = v.y;
    tile[row][seg * 32 + c * 4 + 2] = v.z;
    tile[row][seg * 32 + c * 4 + 3] = v.w;
    ushort4 h;
    h.x = f2bf(v.x); h.y = f2bf(v.y); h.z = f2bf(v.z); h.w = f2bf(v.w);
    ((ushort4*)zn)[c] = h;
  }
  __syncthreads();
  float s = 0.f;
  #pragma unroll
  for (int c = 0; c < 32; ++c) s += tile[row][seg * 32 + c] * wnw[seg * 32 + c];
  s += __shfl_xor(s, 1); s += __shfl_xor(s, 2); s += __shfl_xor(s, 4);
  if (seg == 0){
    float dw = 1.f / (1.f + expf(-(s + bnw[0])));
    aw_out[b * (2 * Nn) + n0 + row] = dw;
    dws[row] = mask[b * Nn + n0 + row] ? dw : 0.f;
  }
  __syncthreads();
  // Xp[n][d] = bf16(dw[n] * node[n][d])  (row-major, col-mask folded)
  {
    float dwr = dws[row];
    u16* xp = Xp + ((size_t)(b * Nn + n0 + row)) * Dd + seg * 32;
    #pragma unroll
    for (int c = 0; c < 8; ++c){
      ushort4 h;
      h.x = f2bf(dwr * tile[row][seg * 32 + c * 4 + 0]);
      h.y = f2bf(dwr * tile[row][seg * 32 + c * 4 + 1]);
      h.z = f2bf(dwr * tile[row][seg * 32 + c * 4 + 2]);
      h.w = f2bf(dwr * tile[row][seg * 32 + c * 4 + 3]);
      ((ushort4*)xp)[c] = h;
    }
  }
}

// ---------------- K3: Ycat GEMM  Yt[b][k][e][n] = (Xp[b] @ W_k)^T ----------
// grid (4, 12, 32): ntile, ctile(128 of 1536), b. 128x128 tile, K=256.
__global__ __launch_bounds__(256) void k_ycat(
    const u16* __restrict__ Xp, const u16* __restrict__ wcatT,
    u16* __restrict__ Yt){
  int n0 = blockIdx.x * 128, c0 = blockIdx.y * 128, b = blockIdx.z;
  int kg = c0 >> 8, eg0 = c0 & 255;
  __shared__ u16 As[128 * 72];
  __shared__ u16 Bs[128 * 72];
  int t = threadIdx.x, lane = t & 63, wid = t >> 6;
  int wm = wid >> 1, wn = wid & 1;
  f32x4 acc[4][4];
  #pragma unroll
  for (int i = 0; i < 4; ++i)
    #pragma unroll
    for (int q = 0; q < 4; ++q) acc[i][q] = (f32x4){0.f, 0.f, 0.f, 0.f};

  for (int ks = 0; ks < 4; ++ks){
    int k0 = ks * 64;
    #pragma unroll
    for (int p = 0; p < 4; ++p){
      int row = p * 32 + (t >> 3);
      *(uint4*)&As[row * 72 + (t & 7) * 8] =
          *(const uint4*)(Xp + ((size_t)(b * Nn + n0 + row)) * Dd + k0 + (t & 7) * 8);
      *(uint4*)&Bs[row * 72 + (t & 7) * 8] =
          *(const uint4*)(wcatT + (size_t)(eg0 + row) * KC + 256 + kg * 256 + k0 + (t & 7) * 8);
    }
    __syncthreads();
    #pragma unroll
    for (int kk = 0; kk < 2; ++kk){
      bf16x8 av[4], bv[4];
      #pragma unroll
      for (int i = 0; i < 4; ++i)
        av[i] = *(const bf16x8*)&As[(wm * 64 + i * 16 + (lane & 15)) * 72 + kk * 32 + (lane >> 4) * 8];
      #pragma unroll
      for (int q = 0; q < 4; ++q)
        bv[q] = *(const bf16x8*)&Bs[(wn * 64 + q * 16 + (lane & 15)) * 72 + kk * 32 + (lane >> 4) * 8];
      #pragma unroll
      for (int i = 0; i < 4; ++i)
        #pragma unroll
        for (int q = 0; q < 4; ++q)
          acc[i][q] = __builtin_amdgcn_mfma_f32_16x16x32_bf16(av[i], bv[q], acc[i][q], 0, 0, 0);
    }
    __syncthreads();
  }
  // epilogue: Yt[((b*6+kg)*256 + eg)][n], bf16, r-quad packed (n consecutive)
  #pragma unroll
  for (int i = 0; i < 4; ++i){
    int nbase = n0 + wm * 64 + i * 16 + (lane >> 4) * 4;
    #pragma unroll
    for (int q = 0; q < 4; ++q){
      int eg = eg0 + wn * 64 + q * 16 + (lane & 15);
      ushort4 h;
      h.x = f2bf(acc[i][q][0]); h.y = f2bf(acc[i][q][1]);
      h.z = f2bf(acc[i][q][2]); h.w = f2bf(acc[i][q][3]);
      *(ushort4*)(Yt + ((size_t)((b * 6 + kg) * 256 + eg)) * Nn + nbase) = h;
    }
  }
}

// ---------------- K4a: ITER-1 aggregation from RAW graphs (R15, stable) ----
__global__ __launch_bounds__(256) void k_agg1(
    const int* __restrict__ g0, const int* __restrict__ g1,
    const int* __restrict__ g2, const int* __restrict__ g3,
    const int* __restrict__ g4, const int* __restrict__ g5,
    const int* __restrict__ mask, const u16* __restrict__ Yt,
    const u16* __restrict__ Nbf, const u16* __restrict__ wcatT,
    const float* __restrict__ bself,
    unsigned char* __restrict__ Gp8, float* __restrict__ rs,
    float* __restrict__ outp){
  __shared__ u16 As[32 * 72];
  __shared__ u16 BW[256 * 72];
  __shared__ int nns[32][9];
  __shared__ float rsl[32];
  __shared__ unsigned char lmask8[64];
  const int* gs[6] = {g0, g1, g2, g3, g4, g5};
  int id = blockIdx.x;
  int xcd = id & 7, q = id >> 3;
  int b = xcd * 4 + (q & 3), mt = q >> 2;
  int m0 = mt * 32;
  int t = threadIdx.x, lane = t & 63, wn = t >> 6;
  int arow = t >> 3, q8 = t & 7;          // A-stage role: row 0..31, 8 cols
  int mloc = m0 + arow;                   // diag col for this row

  if (t < 64){
    const int* mp = mask + (size_t)b * Nn + t * 8;
    unsigned mb = 0;
    #pragma unroll
    for (int j = 0; j < 8; ++j) mb |= (unsigned)(mp[j] & 1) << j;
    lmask8[t] = (unsigned char)mb;
  }
  __syncthreads();

  f32x4 acc[2][4];
  #pragma unroll
  for (int i = 0; i < 2; ++i)
    #pragma unroll
    for (int q2 = 0; q2 < 4; ++q2) acc[i][q2] = (f32x4){0.f, 0.f, 0.f, 0.f};

  int nnp = 0;
  for (int k = 0; k < 6; ++k){
    const int* Gk = gs[k] + ((size_t)(b * Nn + m0)) * Nn;
    const u16* Yk = Yt + ((size_t)((b * 6 + k) * 256)) * Nn;
    for (int ks = 0; ks < 8; ++ks){
      { // A stage: 8 raw ints -> 8-bit mask -> bf16 + popcount + Gp byte
        const i32x4* gp = (const i32x4*)(Gk + (size_t)arow * Nn + ks * 64 + q8 * 8);
        i32x4 x0 = gp[0], x1 = gp[1];
        unsigned bits = (unsigned)((x0[0] & 1) | ((x0[1] & 1) << 1) |
                                   ((x0[2] & 1) << 2) | ((x0[3] & 1) << 3) |
                                   ((x1[0] & 1) << 4) | ((x1[1] & 1) << 5) |
                                   ((x1[2] & 1) << 6) | ((x1[3] & 1) << 7));
        unsigned dm = ((mloc >> 3) == (ks * 8 + q8)) ? (1u << (mloc & 7)) : 0u;
        bits &= ~dm;                      // diag excluded (GEMM + count)
        unsigned mb = lmask8[ks * 8 + q8];
        unsigned bm = bits & mb;          // col-mask for count + Gp
        nnp += __popc(bm);
        Gp8[(((size_t)k * NR + b * Nn + m0 + arow) * 16 + ks * 2 + (q8 >> 2)) * 4 + (q8 & 3)] =
            (unsigned char)bm;
        union { u16 h[8]; uint4 v; } pk;
        #pragma unroll
        for (int c = 0; c < 8; ++c)
          pk.h[c] = ((bits >> c) & 1u) ? 0x3F80 : 0;
        *(uint4*)&As[arow * 72 + q8 * 8] = pk.v;
      }
      #pragma unroll
      for (int p = 0; p < 8; ++p){
        int rowb = p * 32 + (t >> 3);
        *(uint4*)&BW[rowb * 72 + (t & 7) * 8] =
            *(const uint4*)(Yk + (size_t)rowb * Nn + ks * 64 + (t & 7) * 8);
      }
      __syncthreads();
      #pragma unroll
      for (int kk = 0; kk < 2; ++kk){
        bf16x8 av[2], bv[4];
        #pragma unroll
        for (int i = 0; i < 2; ++i)
          av[i] = *(const bf16x8*)&As[(i * 16 + (lane & 15)) * 72 + kk * 32 + (lane >> 4) * 8];
        #pragma unroll
        for (int q2 = 0; q2 < 4; ++q2)
          bv[q2] = *(const bf16x8*)&BW[(wn * 64 + q2 * 16 + (lane & 15)) * 72 + kk * 32 + (lane >> 4) * 8];
        #pragma unroll
        for (int i = 0; i < 2; ++i)
          #pragma unroll
          for (int q2 = 0; q2 < 4; ++q2)
            acc[i][q2] = __builtin_amdgcn_mfma_f32_16x16x32_bf16(av[i], bv[q2], acc[i][q2], 0, 0, 0);
      }
      __syncthreads();
    }
  }
  // ---- nn reduce -> rs (LDS + global) ----
  nns[arow][q8] = nnp;
  __syncthreads();
  if (t < 32){
    int s = 0;
    #pragma unroll
    for (int j = 0; j < 8; ++j) s += nns[t][j];
    int r = b * Nn + m0 + t;
    float v = mask[r] ? 1.0f / (float)(s < 1 ? 1 : s) : 0.0f;
    rsl[t] = v;
    rs[r] = v;
  }
  __syncthreads();
  // ---- scale edge acc by rs, then accumulate self term on top ----
  #pragma unroll
  for (int i = 0; i < 2; ++i)
    #pragma unroll
    for (int rr = 0; rr < 4; ++rr){
      float s = rsl[i * 16 + (lane >> 4) * 4 + rr];
      #pragma unroll
      for (int q2 = 0; q2 < 4; ++q2) acc[i][q2][rr] *= s;
    }
  for (int ds = 0; ds < 4; ++ds){
    if (t < 256){ // A: Nbf tile 32x64
      *(uint4*)&As[(t >> 3) * 72 + (t & 7) * 8] =
          *(const uint4*)(Nbf + ((size_t)(b * Nn + m0 + (t >> 3))) * Dd + ds * 64 + (t & 7) * 8);
    }
    #pragma unroll
    for (int p = 0; p < 8; ++p){
      int rowb = p * 32 + (t >> 3);
      *(uint4*)&BW[rowb * 72 + (t & 7) * 8] =
          *(const uint4*)(wcatT + (size_t)rowb * KC + ds * 64 + (t & 7) * 8);
    }
    __syncthreads();
    #pragma unroll
    for (int kk = 0; kk < 2; ++kk){
      bf16x8 av[2], bv[4];
      #pragma unroll
      for (int i = 0; i < 2; ++i)
        av[i] = *(const bf16x8*)&As[(i * 16 + (lane & 15)) * 72 + kk * 32 + (lane >> 4) * 8];
      #pragma unroll
      for (int q2 = 0; q2 < 4; ++q2)
        bv[q2] = *(const bf16x8*)&BW[(wn * 64 + q2 * 16 + (lane & 15)) * 72 + kk * 32 + (lane >> 4) * 8];
      #pragma unroll
      for (int i = 0; i < 2; ++i)
        #pragma unroll
        for (int q2 = 0; q2 < 4; ++q2)
          acc[i][q2] = __builtin_amdgcn_mfma_f32_16x16x32_bf16(av[i], bv[q2], acc[i][q2], 0, 0, 0);
    }
    __syncthreads();
  }
  // ---- epilogue ----
  #pragma unroll
  for (int i = 0; i < 2; ++i){
    #pragma unroll
    for (int rr = 0; rr < 4; ++rr){
      size_t gr = (size_t)b * Nn + m0 + i * 16 + (lane >> 4) * 4 + rr;
      #pragma unroll
      for (int q2 = 0; q2 < 4; ++q2){
        int col = wn * 64 + q2 * 16 + (lane & 15);
        float v = acc[i][q2][rr] + bself[col];
        outp[gr * Dd + col] = v > 0.f ? v : 0.f;
      }
    }
  }
}

// ---------------- K4b: ITER-2 aggregation, 2-phase LDS double-buffer -------
// Pure C++ (no inline asm): per step s, stage step s+1 into buf^1 (loads
// issue at top, latency hides under MFMA on buf), ONE barrier per step.
// A-bits come from LDS Gq (staged once). LDS 79.9 KB -> 2 blocks/CU.
__global__ __launch_bounds__(256) void k_agg2(
    const unsigned* __restrict__ Gp, const u16* __restrict__ Yt,
    const u16* __restrict__ Nbf, const u16* __restrict__ wcatT,
    const float* __restrict__ rs, const float* __restrict__ bself,
    float* __restrict__ outp){
  __shared__ u16 As[2][64 * 72];
  __shared__ u16 BW[2][128 * 72];
  __shared__ unsigned Gq[6][64][16];
  int id = blockIdx.x;
  int xcd = id & 7, q = id >> 3;
  int b = xcd * 4 + (q & 3), mt = (q >> 2) & 7, z = q >> 5;
  int m0 = mt * 64, e0 = z * 128;
  int t = threadIdx.x, lane = t & 63, wn = t >> 6;
  int arow = t >> 2, aq = t & 3;

  float rsv[16];
  #pragma unroll
  for (int i = 0; i < 4; ++i)
    #pragma unroll
    for (int r = 0; r < 4; ++r)
      rsv[i * 4 + r] = rs[b * Nn + m0 + i * 16 + (lane >> 4) * 4 + r];

  // stage A-words to LDS once (24 KB)
  #pragma unroll
  for (int k = 0; k < 6; ++k){
    const uint4* src = (const uint4*)(Gp + ((size_t)k * NR + b * Nn + m0) * 16) + t;
    *(uint4*)&Gq[k][t >> 2][(t & 3) * 4] = *src;
  }
  __syncthreads();

  f32x4 accA[4][2];
  #pragma unroll
  for (int i = 0; i < 4; ++i)
    #pragma unroll
    for (int q2 = 0; q2 < 2; ++q2)
      accA[i][q2] = (f32x4){0.f, 0.f, 0.f, 0.f};

#define STG(S, B) { int kk_ = (S) >> 3, k8_ = (S) & 7; \
    unsigned w_ = Gq[kk_][arow][k8_ * 2 + (aq >> 1)]; \
    unsigned bits = (w_ >> ((aq & 1) * 16)) & 0xFFFFu; \
    union { u16 h[16]; uint4 v[2]; } pk_; \
    _Pragma("unroll") \
    for (int c = 0; c < 16; ++c) pk_.h[c] = ((bits >> c) & 1u) ? 0x3F80 : 0; \
    *(uint4*)&As[B][arow * 72 + aq * 16]     = pk_.v[0]; \
    *(uint4*)&As[B][arow * 72 + aq * 16 + 8] = pk_.v[1]; \
    const u16* Yk_ = Yt + ((size_t)((b * 6 + kk_) * 256 + e0)) * Nn + k8_ * 64; \
    _Pragma("unroll") \
    for (int p = 0; p < 4; ++p){ \
      int rowb = p * 32 + (t >> 3); \
      *(uint4*)&BW[B][rowb * 72 + (t & 7) * 8] = \
          *(const uint4*)(Yk_ + (size_t)rowb * Nn + (t & 7) * 8); \
    } }

  STG(0, 0);
  __syncthreads();
  int cur = 0;
  for (int s = 0; s < 48; ++s){
    if (s < 47) STG(s + 1, cur ^ 1);
    #pragma unroll
    for (int kk = 0; kk < 2; ++kk){
      bf16x8 av[4], bv[2];
      #pragma unroll
      for (int i = 0; i < 4; ++i)
        av[i] = *(const bf16x8*)&As[cur][(i * 16 + (lane & 15)) * 72 + kk * 32 + (lane >> 4) * 8];
      #pragma unroll
      for (int q2 = 0; q2 < 2; ++q2)
        bv[q2] = *(const bf16x8*)&BW[cur][(wn * 32 + q2 * 16 + (lane & 15)) * 72 + kk * 32 + (lane >> 4) * 8];
      #pragma unroll
      for (int i = 0; i < 4; ++i)
        #pragma unroll
        for (int q2 = 0; q2 < 2; ++q2)
          accA[i][q2] = __builtin_amdgcn_mfma_f32_16x16x32_bf16(av[i], bv[q2], accA[i][q2], 0, 0, 0);
    }
    __syncthreads();
    cur ^= 1;
  }
#undef STG

  // ---- scale by rs, then accumulate self term on top ----
  #pragma unroll
  for (int i = 0; i < 4; ++i)
    #pragma unroll
    for (int rr = 0; rr < 4; ++rr){
      float s = rsv[i * 4 + rr];
      #pragma unroll
      for (int q2 = 0; q2 < 2; ++q2) accA[i][q2][rr] *= s;
    }
  for (int ds = 0; ds < 4; ++ds){
    #pragma unroll
    for (int p = 0; p < 2; ++p){
      int row = p * 32 + (t >> 3);
      *(uint4*)&As[0][row * 72 + (t & 7) * 8] =
          *(const uint4*)(Nbf + ((size_t)(b * Nn + m0 + row)) * Dd + ds * 64 + (t & 7) * 8);
    }
    #pragma unroll
    for (int p = 0; p < 4; ++p){
      int rowb = p * 32 + (t >> 3);
      *(uint4*)&BW[0][rowb * 72 + (t & 7) * 8] =
          *(const uint4*)(wcatT + (size_t)(e0 + rowb) * KC + ds * 64 + (t & 7) * 8);
    }
    __syncthreads();
    #pragma unroll
    for (int kk = 0; kk < 2; ++kk){
      bf16x8 av[4], bv[2];
      #pragma unroll
      for (int i = 0; i < 4; ++i)
        av[i] = *(const bf16x8*)&As[0][(i * 16 + (lane & 15)) * 72 + kk * 32 + (lane >> 4) * 8];
      #pragma unroll
      for (int q2 = 0; q2 < 2; ++q2)
        bv[q2] = *(const bf16x8*)&BW[0][(wn * 32 + q2 * 16 + (lane & 15)) * 72 + kk * 32 + (lane >> 4) * 8];
      #pragma unroll
      for (int i = 0; i < 4; ++i)
        #pragma unroll
        for (int q2 = 0; q2 < 2; ++q2)
          accA[i][q2] = __builtin_amdgcn_mfma_f32_16x16x32_bf16(av[i], bv[q2], accA[i][q2], 0, 0, 0);
    }
    __syncthreads();
  }
  // ---- epilogue ----
  #pragma unroll
  for (int i = 0; i < 4; ++i){
    #pragma unroll
    for (int rr = 0; rr < 4; ++rr){
      size_t gr = (size_t)b * Nn + m0 + i * 16 + (lane >> 4) * 4 + rr;
      #pragma unroll
      for (int q2 = 0; q2 < 2; ++q2){
        int col = e0 + wn * 32 + q2 * 16 + (lane & 15);
        float v = accA[i][q2][rr] + bself[col];
        outp[gr * Dd + col] = v > 0.f ? v : 0.f;
      }
    }
  }
}

extern "C" void kernel_launch(void* const* d_in, const int* in_sizes, int n_in,
                              void* d_out, int out_size, void* d_ws, size_t ws_size,
                              hipStream_t stream){
  (void)in_sizes; (void)n_in; (void)out_size; (void)ws_size;
  const float* node  = (const float*)d_in[0];
  const int*   mask  = (const int*)d_in[1];
  const int*   g[6];
  for (int i = 0; i < 6; ++i) g[i] = (const int*)d_in[2 + i];
  const float* wnw   = (const float*)d_in[8];
  const float* bnw   = (const float*)d_in[9];
  const float* wself = (const float*)d_in[10];
  const float* bself = (const float*)d_in[11];
  const float* W[6];
  for (int i = 0; i < 6; ++i) W[i] = (const float*)d_in[12 + i];

  float* out_node = (float*)d_out;
  float* out_aw   = out_node + (size_t)Bb * Nn * Dd;

  char* ws = (char*)d_ws;
  u16*      wcatT = (u16*)(ws);                    // 917,504 B
  float*    rs    = (float*)(ws + 917504);         // 65,536 B
  unsigned* Gp    = (unsigned*)(ws + 1048576);     // 6,291,456 B
  u16*      Xp    = (u16*)(ws + 7340032);          // 8,388,608 B
  u16*      Nbf   = (u16*)(ws + 15728640);         // 8,388,608 B
  u16*      Yt    = (u16*)(ws + 24117248);         // 50,331,648 B -> ends ~74.4 MB

  k_prep<<<256, 256, 0, stream>>>(wself, W[0], W[1], W[2], W[3], W[4], W[5], wcatT);

  // ---- iteration 1: raw-graph aggregation (also emits Gp, rs) ----
  k_dw<<<512, 256, 0, stream>>>(node, mask, wnw, bnw, out_aw, Nbf, Xp);
  k_ycat<<<dim3(4, 12, 32), 256, 0, stream>>>(Xp, wcatT, Yt);
  k_agg1<<<512, 256, 0, stream>>>(g[0], g[1], g[2], g[3], g[4], g[5], mask,
                                  Yt, Nbf, wcatT, bself,
                                  (unsigned char*)Gp, rs, out_node);

  // ---- iteration 2: packed-graph aggregation ----
  k_dw<<<512, 256, 0, stream>>>(out_node, mask, wnw, bnw, out_aw + Nn, Nbf, Xp);
  k_ycat<<<dim3(4, 12, 32), 256, 0, stream>>>(Xp, wcatT, Yt);
  k_agg2<<<512, 256, 0, stream>>>(Gp, Yt, Nbf, wcatT, rs, bself, out_node);
}

// Round 20
// 233.939 us; speedup vs baseline: 1.0549x; 1.0549x over previous
//
#include <hip/hip_runtime.h>

#define Bb 32
#define Nn 512
#define Dd 256
#define KC 1792   // 256 (self) + 6*256 (edge types)
#define NR (Bb * Nn)   // 16384 rows

typedef __bf16 bf16x8 __attribute__((ext_vector_type(8)));
typedef float  f32x4  __attribute__((ext_vector_type(4)));
typedef int    i32x4  __attribute__((ext_vector_type(4)));
typedef unsigned short u16;

__device__ __forceinline__ u16 f2bf(float x){
  union { float f; unsigned u; } c; c.f = x;
  unsigned u = c.u;
  u += 0x7FFFu + ((u >> 16) & 1u);   // RNE
  return (u16)(u >> 16);
}

// ---------------- K0: WcatT[e][c] = Wcat[c][e] in bf16, [256 x 1792] -------
__global__ __launch_bounds__(256) void k_prep(
    const float* __restrict__ wself,
    const float* __restrict__ w0, const float* __restrict__ w1,
    const float* __restrict__ w2, const float* __restrict__ w3,
    const float* __restrict__ w4, const float* __restrict__ w5,
    u16* __restrict__ wcatT){
  int e = blockIdx.x;
  const float* Ws[7] = {wself, w0, w1, w2, w3, w4, w5};
  for (int c = threadIdx.x; c < KC; c += 256){
    int g = c >> 8, j = c & 255;
    wcatT[(size_t)e*KC + c] = f2bf(Ws[g][j*Dd + e]);
  }
}

// ---------------- K2: dw (sigmoid), Nbf bf16 node copy, Xp = dw*node -------
__global__ __launch_bounds__(256) void k_dw(
    const float* __restrict__ node, const int* __restrict__ mask,
    const float* __restrict__ wnw, const float* __restrict__ bnw,
    float* __restrict__ aw_out,    // already offset by t*N
    u16* __restrict__ Nbf, u16* __restrict__ Xp){
  __shared__ float tile[32][268];
  __shared__ float dws[32];
  int b = blockIdx.x >> 4, n0 = (blockIdx.x & 15) << 5;
  int t = threadIdx.x;
  int row = t >> 3, seg = t & 7;
  const float* src = node + ((size_t)(b * Nn + n0 + row)) * Dd + seg * 32;
  u16* zn = Nbf + ((size_t)(b * Nn + n0 + row)) * Dd + seg * 32;
  #pragma unroll
  for (int c = 0; c < 8; ++c){
    float4 v = ((const float4*)src)[c];
    tile[row][seg * 32 + c * 4 + 0] = v.x;
    tile[row][seg * 32 + c * 4 + 1] = v.y;
    tile[row][seg * 32 + c * 4 + 2] = v.z;
    tile[row][seg * 32 + c * 4 + 3] = v.w;
    ushort4 h;
    h.x = f2bf(v.x); h.y = f2bf(v.y); h.z = f2bf(v.z); h.w = f2bf(v.w);
    ((ushort4*)zn)[c] = h;
  }
  __syncthreads();
  float s = 0.f;
  #pragma unroll
  for (int c = 0; c < 32; ++c) s += tile[row][seg * 32 + c] * wnw[seg * 32 + c];
  s += __shfl_xor(s, 1); s += __shfl_xor(s, 2); s += __shfl_xor(s, 4);
  if (seg == 0){
    float dw = 1.f / (1.f + expf(-(s + bnw[0])));
    aw_out[b * (2 * Nn) + n0 + row] = dw;
    dws[row] = mask[b * Nn + n0 + row] ? dw : 0.f;
  }
  __syncthreads();
  // Xp[n][d] = bf16(dw[n] * node[n][d])  (row-major, col-mask folded)
  {
    float dwr = dws[row];
    u16* xp = Xp + ((size_t)(b * Nn + n0 + row)) * Dd + seg * 32;
    #pragma unroll
    for (int c = 0; c < 8; ++c){
      ushort4 h;
      h.x = f2bf(dwr * tile[row][seg * 32 + c * 4 + 0]);
      h.y = f2bf(dwr * tile[row][seg * 32 + c * 4 + 1]);
      h.z = f2bf(dwr * tile[row][seg * 32 + c * 4 + 2]);
      h.w = f2bf(dwr * tile[row][seg * 32 + c * 4 + 3]);
      ((ushort4*)xp)[c] = h;
    }
  }
}

// ---------------- K3: Ycat GEMM  Yt[b][k][e][n] = (Xp[b] @ W_k)^T ----------
// grid (4, 12, 32): ntile, ctile(128 of 1536), b. 128x128 tile, K=256.
__global__ __launch_bounds__(256) void k_ycat(
    const u16* __restrict__ Xp, const u16* __restrict__ wcatT,
    u16* __restrict__ Yt){
  int n0 = blockIdx.x * 128, c0 = blockIdx.y * 128, b = blockIdx.z;
  int kg = c0 >> 8, eg0 = c0 & 255;
  __shared__ u16 As[128 * 72];
  __shared__ u16 Bs[128 * 72];
  int t = threadIdx.x, lane = t & 63, wid = t >> 6;
  int wm = wid >> 1, wn = wid & 1;
  f32x4 acc[4][4];
  #pragma unroll
  for (int i = 0; i < 4; ++i)
    #pragma unroll
    for (int q = 0; q < 4; ++q) acc[i][q] = (f32x4){0.f, 0.f, 0.f, 0.f};

  for (int ks = 0; ks < 4; ++ks){
    int k0 = ks * 64;
    #pragma unroll
    for (int p = 0; p < 4; ++p){
      int row = p * 32 + (t >> 3);
      *(uint4*)&As[row * 72 + (t & 7) * 8] =
          *(const uint4*)(Xp + ((size_t)(b * Nn + n0 + row)) * Dd + k0 + (t & 7) * 8);
      *(uint4*)&Bs[row * 72 + (t & 7) * 8] =
          *(const uint4*)(wcatT + (size_t)(eg0 + row) * KC + 256 + kg * 256 + k0 + (t & 7) * 8);
    }
    __syncthreads();
    #pragma unroll
    for (int kk = 0; kk < 2; ++kk){
      bf16x8 av[4], bv[4];
      #pragma unroll
      for (int i = 0; i < 4; ++i)
        av[i] = *(const bf16x8*)&As[(wm * 64 + i * 16 + (lane & 15)) * 72 + kk * 32 + (lane >> 4) * 8];
      #pragma unroll
      for (int q = 0; q < 4; ++q)
        bv[q] = *(const bf16x8*)&Bs[(wn * 64 + q * 16 + (lane & 15)) * 72 + kk * 32 + (lane >> 4) * 8];
      #pragma unroll
      for (int i = 0; i < 4; ++i)
        #pragma unroll
        for (int q = 0; q < 4; ++q)
          acc[i][q] = __builtin_amdgcn_mfma_f32_16x16x32_bf16(av[i], bv[q], acc[i][q], 0, 0, 0);
    }
    __syncthreads();
  }
  // epilogue: Yt[((b*6+kg)*256 + eg)][n], bf16, r-quad packed (n consecutive)
  #pragma unroll
  for (int i = 0; i < 4; ++i){
    int nbase = n0 + wm * 64 + i * 16 + (lane >> 4) * 4;
    #pragma unroll
    for (int q = 0; q < 4; ++q){
      int eg = eg0 + wn * 64 + q * 16 + (lane & 15);
      ushort4 h;
      h.x = f2bf(acc[i][q][0]); h.y = f2bf(acc[i][q][1]);
      h.z = f2bf(acc[i][q][2]); h.w = f2bf(acc[i][q][3]);
      *(ushort4*)(Yt + ((size_t)((b * 6 + kg) * 256 + eg)) * Nn + nbase) = h;
    }
  }
}

// ---------------- K4a: ITER-1 aggregation + FUSED iter-2 dw ----------------
// out = relu(rs*(G@Y) + N@Wself + b); side effects: Gp bits, rs, and the
// iter-2 prep: aw2 = sigmoid(out·w_nw+b), Nbf = bf16(out), Xp = dw2*out.
__global__ __launch_bounds__(256) void k_agg1(
    const int* __restrict__ g0, const int* __restrict__ g1,
    const int* __restrict__ g2, const int* __restrict__ g3,
    const int* __restrict__ g4, const int* __restrict__ g5,
    const int* __restrict__ mask, const u16* __restrict__ Yt,
    u16* __restrict__ Nbf, const u16* __restrict__ wcatT,
    const float* __restrict__ bself,
    const float* __restrict__ wnw, const float* __restrict__ bnw,
    unsigned char* __restrict__ Gp8, float* __restrict__ rs,
    float* __restrict__ outp, float* __restrict__ aw2,
    u16* __restrict__ Xp){
  __shared__ u16 As[32 * 72];
  __shared__ u16 BW[256 * 72];
  __shared__ int nns[32][9];
  __shared__ float rsl[32];
  __shared__ unsigned char lmask8[64];
  __shared__ float pdws[4][32];
  __shared__ float dwsl[32];
  const int* gs[6] = {g0, g1, g2, g3, g4, g5};
  int id = blockIdx.x;
  int xcd = id & 7, q = id >> 3;
  int b = xcd * 4 + (q & 3), mt = q >> 2;
  int m0 = mt * 32;
  int t = threadIdx.x, lane = t & 63, wn = t >> 6;
  int arow = t >> 3, q8 = t & 7;          // A-stage role: row 0..31, 8 cols
  int mloc = m0 + arow;                   // diag col for this row

  if (t < 64){
    const int* mp = mask + (size_t)b * Nn + t * 8;
    unsigned mb = 0;
    #pragma unroll
    for (int j = 0; j < 8; ++j) mb |= (unsigned)(mp[j] & 1) << j;
    lmask8[t] = (unsigned char)mb;
  }
  __syncthreads();

  f32x4 acc[2][4];
  #pragma unroll
  for (int i = 0; i < 2; ++i)
    #pragma unroll
    for (int q2 = 0; q2 < 4; ++q2) acc[i][q2] = (f32x4){0.f, 0.f, 0.f, 0.f};

  int nnp = 0;
  for (int k = 0; k < 6; ++k){
    const int* Gk = gs[k] + ((size_t)(b * Nn + m0)) * Nn;
    const u16* Yk = Yt + ((size_t)((b * 6 + k) * 256)) * Nn;
    for (int ks = 0; ks < 8; ++ks){
      { // A stage: 8 raw ints -> 8-bit mask -> bf16 + popcount + Gp byte
        const i32x4* gp = (const i32x4*)(Gk + (size_t)arow * Nn + ks * 64 + q8 * 8);
        i32x4 x0 = gp[0], x1 = gp[1];
        unsigned bits = (unsigned)((x0[0] & 1) | ((x0[1] & 1) << 1) |
                                   ((x0[2] & 1) << 2) | ((x0[3] & 1) << 3) |
                                   ((x1[0] & 1) << 4) | ((x1[1] & 1) << 5) |
                                   ((x1[2] & 1) << 6) | ((x1[3] & 1) << 7));
        unsigned dm = ((mloc >> 3) == (ks * 8 + q8)) ? (1u << (mloc & 7)) : 0u;
        bits &= ~dm;                      // diag excluded (GEMM + count)
        unsigned mb = lmask8[ks * 8 + q8];
        unsigned bm = bits & mb;          // col-mask for count + Gp
        nnp += __popc(bm);
        Gp8[(((size_t)k * NR + b * Nn + m0 + arow) * 16 + ks * 2 + (q8 >> 2)) * 4 + (q8 & 3)] =
            (unsigned char)bm;
        union { u16 h[8]; uint4 v; } pk;
        #pragma unroll
        for (int c = 0; c < 8; ++c)
          pk.h[c] = ((bits >> c) & 1u) ? 0x3F80 : 0;
        *(uint4*)&As[arow * 72 + q8 * 8] = pk.v;
      }
      #pragma unroll
      for (int p = 0; p < 8; ++p){
        int rowb = p * 32 + (t >> 3);
        *(uint4*)&BW[rowb * 72 + (t & 7) * 8] =
            *(const uint4*)(Yk + (size_t)rowb * Nn + ks * 64 + (t & 7) * 8);
      }
      __syncthreads();
      #pragma unroll
      for (int kk = 0; kk < 2; ++kk){
        bf16x8 av[2], bv[4];
        #pragma unroll
        for (int i = 0; i < 2; ++i)
          av[i] = *(const bf16x8*)&As[(i * 16 + (lane & 15)) * 72 + kk * 32 + (lane >> 4) * 8];
        #pragma unroll
        for (int q2 = 0; q2 < 4; ++q2)
          bv[q2] = *(const bf16x8*)&BW[(wn * 64 + q2 * 16 + (lane & 15)) * 72 + kk * 32 + (lane >> 4) * 8];
        #pragma unroll
        for (int i = 0; i < 2; ++i)
          #pragma unroll
          for (int q2 = 0; q2 < 4; ++q2)
            acc[i][q2] = __builtin_amdgcn_mfma_f32_16x16x32_bf16(av[i], bv[q2], acc[i][q2], 0, 0, 0);
      }
      __syncthreads();
    }
  }
  // ---- nn reduce -> rs (LDS + global) ----
  nns[arow][q8] = nnp;
  __syncthreads();
  if (t < 32){
    int s = 0;
    #pragma unroll
    for (int j = 0; j < 8; ++j) s += nns[t][j];
    int r = b * Nn + m0 + t;
    float v = mask[r] ? 1.0f / (float)(s < 1 ? 1 : s) : 0.0f;
    rsl[t] = v;
    rs[r] = v;
  }
  __syncthreads();
  // ---- scale edge acc by rs, then accumulate self term on top ----
  #pragma unroll
  for (int i = 0; i < 2; ++i)
    #pragma unroll
    for (int rr = 0; rr < 4; ++rr){
      float s = rsl[i * 16 + (lane >> 4) * 4 + rr];
      #pragma unroll
      for (int q2 = 0; q2 < 4; ++q2) acc[i][q2][rr] *= s;
    }
  for (int ds = 0; ds < 4; ++ds){
    *(uint4*)&As[(t >> 3) * 72 + (t & 7) * 8] =
        *(const uint4*)(Nbf + ((size_t)(b * Nn + m0 + (t >> 3))) * Dd + ds * 64 + (t & 7) * 8);
    #pragma unroll
    for (int p = 0; p < 8; ++p){
      int rowb = p * 32 + (t >> 3);
      *(uint4*)&BW[rowb * 72 + (t & 7) * 8] =
          *(const uint4*)(wcatT + (size_t)rowb * KC + ds * 64 + (t & 7) * 8);
    }
    __syncthreads();
    #pragma unroll
    for (int kk = 0; kk < 2; ++kk){
      bf16x8 av[2], bv[4];
      #pragma unroll
      for (int i = 0; i < 2; ++i)
        av[i] = *(const bf16x8*)&As[(i * 16 + (lane & 15)) * 72 + kk * 32 + (lane >> 4) * 8];
      #pragma unroll
      for (int q2 = 0; q2 < 4; ++q2)
        bv[q2] = *(const bf16x8*)&BW[(wn * 64 + q2 * 16 + (lane & 15)) * 72 + kk * 32 + (lane >> 4) * 8];
      #pragma unroll
      for (int i = 0; i < 2; ++i)
        #pragma unroll
        for (int q2 = 0; q2 < 4; ++q2)
          acc[i][q2] = __builtin_amdgcn_mfma_f32_16x16x32_bf16(av[i], bv[q2], acc[i][q2], 0, 0, 0);
    }
    __syncthreads();
  }
  // ---- epilogue: relu -> out + Nbf(bf16); fused iter-2 dw -> aw2, Xp ----
  float wnwv[4];
  #pragma unroll
  for (int q2 = 0; q2 < 4; ++q2) wnwv[q2] = wnw[wn * 64 + q2 * 16 + (lane & 15)];
  float pd[2][4];
  #pragma unroll
  for (int i = 0; i < 2; ++i){
    #pragma unroll
    for (int rr = 0; rr < 4; ++rr){
      size_t gr = (size_t)b * Nn + m0 + i * 16 + (lane >> 4) * 4 + rr;
      float p = 0.f;
      #pragma unroll
      for (int q2 = 0; q2 < 4; ++q2){
        int col = wn * 64 + q2 * 16 + (lane & 15);
        float v = acc[i][q2][rr] + bself[col];
        v = v > 0.f ? v : 0.f;
        acc[i][q2][rr] = v;                 // keep f32 for Xp
        outp[gr * Dd + col] = v;
        Nbf[gr * Dd + col] = f2bf(v);
        p += v * wnwv[q2];
      }
      pd[i][rr] = p;
    }
  }
  #pragma unroll
  for (int i = 0; i < 2; ++i)
    #pragma unroll
    for (int rr = 0; rr < 4; ++rr){
      float s = pd[i][rr];
      s += __shfl_xor(s, 1); s += __shfl_xor(s, 2);
      s += __shfl_xor(s, 4); s += __shfl_xor(s, 8);
      pd[i][rr] = s;
    }
  if ((lane & 15) == 0){
    #pragma unroll
    for (int i = 0; i < 2; ++i)
      #pragma unroll
      for (int rr = 0; rr < 4; ++rr)
        pdws[wn][i * 16 + (lane >> 4) * 4 + rr] = pd[i][rr];
  }
  __syncthreads();
  if (t < 32){
    float dot = pdws[0][t] + pdws[1][t] + pdws[2][t] + pdws[3][t];
    float dwv = 1.f / (1.f + expf(-(dot + bnw[0])));
    aw2[b * (2 * Nn) + m0 + t] = dwv;       // aw2 pre-offset by +Nn (t=1 slot)
    dwsl[t] = mask[b * Nn + m0 + t] ? dwv : 0.f;
  }
  __syncthreads();
  #pragma unroll
  for (int i = 0; i < 2; ++i)
    #pragma unroll
    for (int rr = 0; rr < 4; ++rr){
      int rl = i * 16 + (lane >> 4) * 4 + rr;
      size_t gr = (size_t)b * Nn + m0 + rl;
      float dwv = dwsl[rl];
      #pragma unroll
      for (int q2 = 0; q2 < 4; ++q2){
        int col = wn * 64 + q2 * 16 + (lane & 15);
        Xp[gr * Dd + col] = f2bf(dwv * acc[i][q2][rr]);
      }
    }
}

// ---------------- K4b: ITER-2 aggregation from PACKED graphs (R17 form) ----
__global__ __launch_bounds__(256) void k_agg2(
    const unsigned* __restrict__ Gp, const u16* __restrict__ Yt,
    const u16* __restrict__ Nbf, const u16* __restrict__ wcatT,
    const float* __restrict__ rs, const float* __restrict__ bself,
    float* __restrict__ outp){
  __shared__ u16 As[64 * 72];
  __shared__ u16 BW[128 * 72];
  int id = blockIdx.x;
  int xcd = id & 7, q = id >> 3;
  int b = xcd * 4 + (q & 3), mt = (q >> 2) & 7, z = q >> 5;
  int m0 = mt * 64, e0 = z * 128;
  int t = threadIdx.x, lane = t & 63, wn = t >> 6;
  int arow = t >> 2, aq = t & 3;

  float rsv[16];
  #pragma unroll
  for (int i = 0; i < 4; ++i)
    #pragma unroll
    for (int r = 0; r < 4; ++r)
      rsv[i * 4 + r] = rs[b * Nn + m0 + i * 16 + (lane >> 4) * 4 + r];

  f32x4 accA[4][2];
  #pragma unroll
  for (int i = 0; i < 4; ++i)
    #pragma unroll
    for (int q2 = 0; q2 < 2; ++q2)
      accA[i][q2] = (f32x4){0.f, 0.f, 0.f, 0.f};

  for (int k = 0; k < 6; ++k){
    const unsigned* Gr = Gp + ((size_t)k * NR + b * Nn + m0) * 16;
    unsigned wpre[8];
    #pragma unroll
    for (int ks2 = 0; ks2 < 8; ++ks2)
      wpre[ks2] = Gr[arow * 16 + ks2 * 2 + (aq >> 1)];
    const u16* Yk = Yt + ((size_t)((b * 6 + k) * 256)) * Nn;

    for (int ks2 = 0; ks2 < 8; ++ks2){
      { // A stage: unpack 16 bits -> bf16 0/1
        unsigned bits = (wpre[ks2] >> ((aq & 1) * 16)) & 0xFFFFu;
        union { u16 h[16]; uint4 v[2]; } pk;
        #pragma unroll
        for (int c = 0; c < 16; ++c)
          pk.h[c] = ((bits >> c) & 1u) ? 0x3F80 : 0;
        *(uint4*)&As[arow * 72 + aq * 16]     = pk.v[0];
        *(uint4*)&As[arow * 72 + aq * 16 + 8] = pk.v[1];
      }
      #pragma unroll
      for (int p = 0; p < 4; ++p){
        int rowb = p * 32 + (t >> 3);
        *(uint4*)&BW[rowb * 72 + (t & 7) * 8] =
            *(const uint4*)(Yk + (size_t)(e0 + rowb) * Nn + ks2 * 64 + (t & 7) * 8);
      }
      __syncthreads();
      #pragma unroll
      for (int kk = 0; kk < 2; ++kk){
        bf16x8 av[4], bv[2];
        #pragma unroll
        for (int i = 0; i < 4; ++i)
          av[i] = *(const bf16x8*)&As[(i * 16 + (lane & 15)) * 72 + kk * 32 + (lane >> 4) * 8];
        #pragma unroll
        for (int q2 = 0; q2 < 2; ++q2)
          bv[q2] = *(const bf16x8*)&BW[(wn * 32 + q2 * 16 + (lane & 15)) * 72 + kk * 32 + (lane >> 4) * 8];
        #pragma unroll
        for (int i = 0; i < 4; ++i)
          #pragma unroll
          for (int q2 = 0; q2 < 2; ++q2)
            accA[i][q2] = __builtin_amdgcn_mfma_f32_16x16x32_bf16(av[i], bv[q2], accA[i][q2], 0, 0, 0);
      }
      __syncthreads();
    }
  }
  // ---- scale by rs, then accumulate self term on top ----
  #pragma unroll
  for (int i = 0; i < 4; ++i)
    #pragma unroll
    for (int rr = 0; rr < 4; ++rr){
      float s = rsv[i * 4 + rr];
      #pragma unroll
      for (int q2 = 0; q2 < 2; ++q2) accA[i][q2][rr] *= s;
    }
  for (int ds = 0; ds < 4; ++ds){
    #pragma unroll
    for (int p = 0; p < 2; ++p){
      int row = p * 32 + (t >> 3);
      *(uint4*)&As[row * 72 + (t & 7) * 8] =
          *(const uint4*)(Nbf + ((size_t)(b * Nn + m0 + row)) * Dd + ds * 64 + (t & 7) * 8);
    }
    #pragma unroll
    for (int p = 0; p < 4; ++p){
      int rowb = p * 32 + (t >> 3);
      *(uint4*)&BW[rowb * 72 + (t & 7) * 8] =
          *(const uint4*)(wcatT + (size_t)(e0 + rowb) * KC + ds * 64 + (t & 7) * 8);
    }
    __syncthreads();
    #pragma unroll
    for (int kk = 0; kk < 2; ++kk){
      bf16x8 av[4], bv[2];
      #pragma unroll
      for (int i = 0; i < 4; ++i)
        av[i] = *(const bf16x8*)&As[(i * 16 + (lane & 15)) * 72 + kk * 32 + (lane >> 4) * 8];
      #pragma unroll
      for (int q2 = 0; q2 < 2; ++q2)
        bv[q2] = *(const bf16x8*)&BW[(wn * 32 + q2 * 16 + (lane & 15)) * 72 + kk * 32 + (lane >> 4) * 8];
      #pragma unroll
      for (int i = 0; i < 4; ++i)
        #pragma unroll
        for (int q2 = 0; q2 < 2; ++q2)
          accA[i][q2] = __builtin_amdgcn_mfma_f32_16x16x32_bf16(av[i], bv[q2], accA[i][q2], 0, 0, 0);
    }
    __syncthreads();
  }
  // ---- epilogue ----
  #pragma unroll
  for (int i = 0; i < 4; ++i){
    #pragma unroll
    for (int rr = 0; rr < 4; ++rr){
      size_t gr = (size_t)b * Nn + m0 + i * 16 + (lane >> 4) * 4 + rr;
      #pragma unroll
      for (int q2 = 0; q2 < 2; ++q2){
        int col = e0 + wn * 32 + q2 * 16 + (lane & 15);
        float v = accA[i][q2][rr] + bself[col];
        outp[gr * Dd + col] = v > 0.f ? v : 0.f;
      }
    }
  }
}

extern "C" void kernel_launch(void* const* d_in, const int* in_sizes, int n_in,
                              void* d_out, int out_size, void* d_ws, size_t ws_size,
                              hipStream_t stream){
  (void)in_sizes; (void)n_in; (void)out_size; (void)ws_size;
  const float* node  = (const float*)d_in[0];
  const int*   mask  = (const int*)d_in[1];
  const int*   g[6];
  for (int i = 0; i < 6; ++i) g[i] = (const int*)d_in[2 + i];
  const float* wnw   = (const float*)d_in[8];
  const float* bnw   = (const float*)d_in[9];
  const float* wself = (const float*)d_in[10];
  const float* bself = (const float*)d_in[11];
  const float* W[6];
  for (int i = 0; i < 6; ++i) W[i] = (const float*)d_in[12 + i];

  float* out_node = (float*)d_out;
  float* out_aw   = out_node + (size_t)Bb * Nn * Dd;

  char* ws = (char*)d_ws;
  u16*      wcatT = (u16*)(ws);                    // 917,504 B
  float*    rs    = (float*)(ws + 917504);         // 65,536 B
  unsigned* Gp    = (unsigned*)(ws + 1048576);     // 6,291,456 B
  u16*      Xp    = (u16*)(ws + 7340032);          // 8,388,608 B
  u16*      Nbf   = (u16*)(ws + 15728640);         // 8,388,608 B
  u16*      Yt    = (u16*)(ws + 24117248);         // 50,331,648 B -> ends ~74.4 MB

  k_prep<<<256, 256, 0, stream>>>(wself, W[0], W[1], W[2], W[3], W[4], W[5], wcatT);

  // ---- iteration 1: raw-graph aggregation (emits Gp, rs, and iter-2 prep) --
  k_dw<<<512, 256, 0, stream>>>(node, mask, wnw, bnw, out_aw, Nbf, Xp);
  k_ycat<<<dim3(4, 12, 32), 256, 0, stream>>>(Xp, wcatT, Yt);
  k_agg1<<<512, 256, 0, stream>>>(g[0], g[1], g[2], g[3], g[4], g[5], mask,
                                  Yt, Nbf, wcatT, bself, wnw, bnw,
                                  (unsigned char*)Gp, rs, out_node,
                                  out_aw + Nn, Xp);

  // ---- iteration 2: packed-graph aggregation (dw already fused in agg1) ---
  k_ycat<<<dim3(4, 12, 32), 256, 0, stream>>>(Xp, wcatT, Yt);
  k_agg2<<<512, 256, 0, stream>>>(Gp, Yt, Nbf, wcatT, rs, bself, out_node);
}